// Round 12
// baseline (281.517 us; speedup 1.0000x reference)
//
#include <hip/hip_runtime.h>

#define B_DIM 64
#define T_DIM 524288
#define D_FAC 16
#define LBLK 64          // frames per composed block
#define NB 512           // blocks per row
#define NBLK_TOT 32768   // total blocks (B*NB)
#define CSTR 72          // padded stride (floats) of one block map (16B-aligned)
#define PF 8             // K2 prefetch depth (blocks)
#define EPSV 1e-7f
#define BIGC 1e30f

// 20*log10(2)
#define DB_PER_LOG2 6.0205999132796239f
// log2(10)/20
#define L2TEN_OVER20 0.16609640474436813f

__device__ __forceinline__ float sum_log2_4(float4 x) {
  return __log2f(fabsf(x.x) + EPSV) + __log2f(fabsf(x.y) + EPSV) +
         __log2f(fabsf(x.z) + EPSV) + __log2f(fabsf(x.w) + EPSV);
}

template <int CTRL, int RM>
__device__ __forceinline__ float fmin_dpp_step(float v) {
  int vi = __float_as_int(v);
  int sh = __builtin_amdgcn_update_dpp(vi, vi, CTRL, RM, 0xf, false);
  return fminf(v, __int_as_float(sh));
}

// K1: one wave per 64-frame block; lane = class; class-parallel DP via DPP
// wave_shr:1 (r8/r10 version). Class 64 replicated into slots 64..71 so
// K2's lane 8 reads it as two float4.
// DIAGNOSTIC (this round): launched 4x to make its duration and counters
// visible above the harness's 75us fill dispatches. Idempotent.
__global__ __launch_bounds__(256) void k1_compose(
    const float* __restrict__ audio, const float* __restrict__ p_thr,
    const float* __restrict__ p_ratio, const float* __restrict__ p_att,
    const float* __restrict__ p_rel, float* __restrict__ consts) {
  const int tid = threadIdx.x;
  const int lane = tid & 63;
  const int w = tid >> 6;
  const int gblk = blockIdx.x * 4 + w;  // 0..32767
  const int row = gblk >> 9;
  const int b = gblk & (NB - 1);
  const float thr = p_thr[0];
  const float A = p_att[0], R = p_rel[0];
  const float oneA = 1.f - A, oneR = 1.f - R;
  const float gslope = (1.f / p_ratio[0]) - 1.f;

  const size_t sbase = (size_t)row * T_DIM + (size_t)(b * LBLK + lane) * D_FAC;
  const float4* ap = (const float4*)(audio + sbase);
  float s = sum_log2_4(ap[0]) + sum_log2_4(ap[1]) + sum_log2_4(ap[2]) +
            sum_log2_4(ap[3]);
  float xdb = s * (DB_PER_LOG2 / 16.f);
  float g = fminf(0.f, (xdb - thr) * gslope);
  const int gi = __float_as_int(g);

  float c = (lane == 0) ? 0.f : BIGC;
  float c64 = BIGC;
#pragma unroll
  for (int t = 0; t < LBLK; ++t) {
    float gt = __int_as_float(__builtin_amdgcn_readlane(gi, t));
    float ca = oneA * gt, cr = oneR * gt;
    float prev = __int_as_float(__builtin_amdgcn_update_dpp(
        __float_as_int(BIGC), __float_as_int(c), 0x138 /*wave_shr:1*/, 0xf,
        0xf, false));
    c64 = fminf(fmaf(A, c, ca), fmaf(R, c64, cr));  // uses c63_old on lane 63
    c = fminf(fmaf(A, prev, ca), fmaf(R, c, cr));
  }
  float* outp = consts + (size_t)gblk * CSTR;
  outp[lane] = c;
  if (lane == 63) {
#pragma unroll
    for (int j = 0; j < 8; ++j) outp[64 + j] = c64;
  }
}

// K2: serial scan, one wave per row (r10 version, best measured). 8 classes
// per lane: lane l in [0,8) holds classes 8l..8l+7 (two float4); lane 8
// holds class 64 (replicated). Per step: 8 fma + min tree + 4 DPP stages +
// readlane(8). Lanes 9..63 compute garbage never read by the reduce.
__global__ __launch_bounds__(64) void k2_scan(const float* __restrict__ consts,
                                              float* __restrict__ states,
                                              const float* __restrict__ p_att,
                                              const float* __restrict__ p_rel) {
  const int r = blockIdx.x;
  const int lane = threadIdx.x;
  const float A = p_att[0], R = p_rel[0];
  const int cls0 = (lane < 8) ? 8 * lane : 64;
  float s0 = 1.f;
  for (int i = 0; i < 64; ++i) s0 *= (i < cls0) ? A : R;  // A^cls0 R^(64-cls0)
  const float rAR = A / R;
  const float sl0 = s0, sl1 = sl0 * rAR, sl2 = sl1 * rAR, sl3 = sl2 * rAR,
              sl4 = sl3 * rAR, sl5 = sl4 * rAR, sl6 = sl5 * rAR,
              sl7 = sl6 * rAR;

  const float* base = consts + (size_t)r * NB * CSTR;
  float* st = states + r * NB;
  const int loff = (lane < 8) ? 8 * lane : 64;

  float4 qa[PF], qb[PF];
#pragma unroll
  for (int u = 0; u < PF; ++u) {
    qa[u] = *(const float4*)(base + u * CSTR + loff);
    qb[u] = *(const float4*)(base + u * CSTR + loff + 4);
  }

  float p = 0.f;
  for (int j = 0; j < 8; ++j) {       // 8 groups of 64 steps
    float sj = 0.f;                   // lane i holds state of block j*64+i
    for (int k = 0; k < 8; ++k) {     // 8 sub-groups of PF=8
#pragma unroll
      for (int u = 0; u < PF; ++u) {
        const int b = j * 64 + k * PF + u;
        const int i = k * PF + u;  // step within group (uniform)
        float f0 = fmaf(sl0, p, qa[u].x);
        float f1 = fmaf(sl1, p, qa[u].y);
        float f2 = fmaf(sl2, p, qa[u].z);
        float f3 = fmaf(sl3, p, qa[u].w);
        float f4 = fmaf(sl4, p, qb[u].x);
        float f5 = fmaf(sl5, p, qb[u].y);
        float f6 = fmaf(sl6, p, qb[u].z);
        float f7 = fmaf(sl7, p, qb[u].w);
        float m = fminf(fminf(fminf(f0, f1), f2),
                        fminf(fminf(fminf(f3, f4), f5), fminf(f6, f7)));
        m = fmin_dpp_step<0x111, 0xf>(m);  // row_shr:1
        m = fmin_dpp_step<0x112, 0xf>(m);  // row_shr:2
        m = fmin_dpp_step<0x114, 0xf>(m);  // row_shr:4 -> lane7 = min(0..7)
        m = fmin_dpp_step<0x111, 0xf>(m);  // fold lane7 agg into lane8
        sj = (lane == i) ? p : sj;  // state at START of block b (old p)
        p = __int_as_float(__builtin_amdgcn_readlane(__float_as_int(m), 8));
        // refill slot u for block b+PF (buffer padded; no tail branch)
        qa[u] = *(const float4*)(base + (b + PF) * CSTR + loff);
        qb[u] = *(const float4*)(base + (b + PF) * CSTR + loff + 4);
      }
    }
    st[j * 64 + lane] = sj;
  }
}

// K3: one wave per block; lane owns one frame (16 samples in regs); wave
// replays the 64-step recurrence from the block-start state; applies gain.
__global__ __launch_bounds__(256) void k3_apply(
    const float* __restrict__ audio, const float* __restrict__ states,
    const float* __restrict__ p_thr, const float* __restrict__ p_ratio,
    const float* __restrict__ p_makeup, const float* __restrict__ p_att,
    const float* __restrict__ p_rel, float* __restrict__ out) {
  const int tid = threadIdx.x;
  const int lane = tid & 63;
  const int w = tid >> 6;
  const int gblk = blockIdx.x * 4 + w;  // 0..32767
  const int row = gblk >> 9;
  const int b = gblk & (NB - 1);
  const float thr = p_thr[0], ratio = p_ratio[0], mk = p_makeup[0];
  const float A = p_att[0], R = p_rel[0];
  const float oneA = 1.f - A, oneR = 1.f - R;
  const float gslope = (1.f / ratio) - 1.f;

  const size_t sbase = (size_t)row * T_DIM + (size_t)(b * LBLK + lane) * D_FAC;
  const float4* ap = (const float4*)(audio + sbase);
  float4 x0 = ap[0], x1 = ap[1], x2 = ap[2], x3 = ap[3];
  float s = sum_log2_4(x0) + sum_log2_4(x1) + sum_log2_4(x2) + sum_log2_4(x3);
  float xdb = s * (DB_PER_LOG2 / 16.f);
  float g = fminf(0.f, (xdb - thr) * gslope);

  float p = states[gblk];
  float m = 0.f;
  int gi = __float_as_int(g);
#pragma unroll
  for (int t = 0; t < LBLK; ++t) {
    float gt = __int_as_float(__builtin_amdgcn_readlane(gi, t));
    p = fminf(fmaf(A, p, oneA * gt), fmaf(R, p, oneR * gt));
    m = (lane == t) ? p : m;
  }
  float mult = exp2f((m + mk) * L2TEN_OVER20);
  float4* op = (float4*)(out + sbase);
  float4 y0, y1, y2, y3;
  y0.x = x0.x * mult; y0.y = x0.y * mult; y0.z = x0.z * mult; y0.w = x0.w * mult;
  y1.x = x1.x * mult; y1.y = x1.y * mult; y1.z = x1.z * mult; y1.w = x1.w * mult;
  y2.x = x2.x * mult; y2.y = x2.y * mult; y2.z = x2.z * mult; y2.w = x2.w * mult;
  y3.x = x3.x * mult; y3.y = x3.y * mult; y3.z = x3.z * mult; y3.w = x3.w * mult;
  op[0] = y0; op[1] = y1; op[2] = y2; op[3] = y3;
}

extern "C" void kernel_launch(void* const* d_in, const int* in_sizes, int n_in,
                              void* d_out, int out_size, void* d_ws,
                              size_t ws_size, hipStream_t stream) {
  const float* audio = (const float*)d_in[0];
  const float* thr = (const float*)d_in[1];
  const float* ratio = (const float*)d_in[2];
  const float* makeup = (const float*)d_in[3];
  const float* att = (const float*)d_in[4];
  const float* rel = (const float*)d_in[5];
  float* out = (float*)d_out;

  const size_t CONSTS_BYTES = (size_t)NBLK_TOT * CSTR * sizeof(float);  // ~9.4 MB
  const size_t PAD_BYTES = (size_t)PF * CSTR * sizeof(float);           // tail prefetch pad
  const size_t STATES_BYTES = (size_t)NBLK_TOT * sizeof(float);         // 128 KB

  float* consts;
  float* states;
  if (ws_size >= CONSTS_BYTES + PAD_BYTES + STATES_BYTES) {
    consts = (float*)d_ws;
    states = (float*)((char*)d_ws + CONSTS_BYTES + PAD_BYTES);
  } else {
    consts = (float*)d_out;
    states = (float*)d_ws;
  }

  // DIAGNOSTIC: k1 launched 4x (idempotent). dur_us = T142 + 3*k1 and, if
  // k1 >= ~73us, its counter rows surface above the harness fills.
  for (int rep = 0; rep < 4; ++rep) {
    hipLaunchKernelGGL(k1_compose, dim3(8192), dim3(256), 0, stream, audio,
                       thr, ratio, att, rel, consts);
  }
  hipLaunchKernelGGL(k2_scan, dim3(64), dim3(64), 0, stream, consts, states,
                     att, rel);
  hipLaunchKernelGGL(k3_apply, dim3(8192), dim3(256), 0, stream, audio, states,
                     thr, ratio, makeup, att, rel, out);
}

// Round 14
// 181.499 us; speedup vs baseline: 1.5511x; 1.5511x over previous
//
#include <hip/hip_runtime.h>

#define B_DIM 64
#define T_DIM 524288
#define D_FAC 16
#define LBLK 64          // frames per composed block
#define NB 512           // blocks per row
#define NBLK_TOT 32768   // total blocks (B*NB)
#define CSTR 72          // padded stride (floats) of one block map (16B-aligned)
#define PF 16            // K2 prefetch depth (blocks)
#define EPSV 1e-7f
#define BIGC 1e30f

// 20*log10(2)
#define DB_PER_LOG2 6.0205999132796239f
// log2(10)/20
#define L2TEN_OVER20 0.16609640474436813f

typedef float vfloat4 __attribute__((ext_vector_type(4)));

__device__ __forceinline__ float sum_log2_4(float4 x) {
  return __log2f(fabsf(x.x) + EPSV) + __log2f(fabsf(x.y) + EPSV) +
         __log2f(fabsf(x.z) + EPSV) + __log2f(fabsf(x.w) + EPSV);
}

template <int CTRL, int RM>
__device__ __forceinline__ float fmin_dpp_step(float v) {
  int vi = __float_as_int(v);
  int sh = __builtin_amdgcn_update_dpp(vi, vi, CTRL, RM, 0xf, false);
  return fminf(v, __int_as_float(sh));
}

// K1: one wave per 64-frame block; lane = class; class-parallel DP via DPP
// wave_shr:1. ca/cr broadcast from LDS via uniform-address float2 reads
// (replaces readlane->SGPR->mov->2xmul: 11 -> 8 inst/step). Class 64
// replicated into slots 64..71 so K2's lane 8 reads it as two float4.
__global__ __launch_bounds__(256) void k1_compose(
    const float* __restrict__ audio, const float* __restrict__ p_thr,
    const float* __restrict__ p_ratio, const float* __restrict__ p_att,
    const float* __restrict__ p_rel, float* __restrict__ consts) {
  __shared__ float cab[4][128];  // per wave: [2t]=ca_t, [2t+1]=cr_t
  const int tid = threadIdx.x;
  const int lane = tid & 63;
  const int w = tid >> 6;
  const int gblk = blockIdx.x * 4 + w;  // 0..32767
  const int row = gblk >> 9;
  const int b = gblk & (NB - 1);
  const float thr = p_thr[0];
  const float A = p_att[0], R = p_rel[0];
  const float oneA = 1.f - A, oneR = 1.f - R;
  const float gslope = (1.f / p_ratio[0]) - 1.f;

  const size_t sbase = (size_t)row * T_DIM + (size_t)(b * LBLK + lane) * D_FAC;
  const float4* ap = (const float4*)(audio + sbase);
  float s = sum_log2_4(ap[0]) + sum_log2_4(ap[1]) + sum_log2_4(ap[2]) +
            sum_log2_4(ap[3]);
  float xdb = s * (DB_PER_LOG2 / 16.f);
  float g = fminf(0.f, (xdb - thr) * gslope);

  // stage ca/cr for all t (same-wave ds_write -> ds_read, in-order)
  cab[w][2 * lane] = oneA * g;
  cab[w][2 * lane + 1] = oneR * g;

  const float2* cp = (const float2*)cab[w];
  float c = (lane == 0) ? 0.f : BIGC;
  float c64 = BIGC;
#pragma unroll
  for (int t = 0; t < LBLK; ++t) {
    float2 cc = cp[t];  // uniform address -> LDS broadcast
    float prev = __int_as_float(__builtin_amdgcn_update_dpp(
        __float_as_int(BIGC), __float_as_int(c), 0x138 /*wave_shr:1*/, 0xf,
        0xf, false));
    c64 = fminf(fmaf(A, c, cc.x), fmaf(R, c64, cc.y));  // c63_old on lane 63
    c = fminf(fmaf(A, prev, cc.x), fmaf(R, c, cc.y));
  }
  float* outp = consts + (size_t)gblk * CSTR;
  outp[lane] = c;
  if (lane == 63) {
#pragma unroll
    for (int j = 0; j < 8; ++j) outp[64 + j] = c64;
  }
}

// K2: serial scan, one wave per row. 8 classes per lane (lanes 0-7, two
// float4 each); lane 8 holds class 64 (replicated). Per step: 8 fma + min
// tree + 4 DPP stages + readlane(8). PF=16 register prefetch (~1300cyc
// latency cover for cross-XCD consts reads at 1 wave/CU). Lanes 9..63
// compute garbage never read by the reduce (row_shr pulls lower lanes).
__global__ __launch_bounds__(64) void k2_scan(const float* __restrict__ consts,
                                              float* __restrict__ states,
                                              const float* __restrict__ p_att,
                                              const float* __restrict__ p_rel) {
  const int r = blockIdx.x;
  const int lane = threadIdx.x;
  const float A = p_att[0], R = p_rel[0];
  const int cls0 = (lane < 8) ? 8 * lane : 64;
  float s0 = 1.f;
  for (int i = 0; i < 64; ++i) s0 *= (i < cls0) ? A : R;  // A^cls0 R^(64-cls0)
  const float rAR = A / R;
  const float sl0 = s0, sl1 = sl0 * rAR, sl2 = sl1 * rAR, sl3 = sl2 * rAR,
              sl4 = sl3 * rAR, sl5 = sl4 * rAR, sl6 = sl5 * rAR,
              sl7 = sl6 * rAR;

  const float* base = consts + (size_t)r * NB * CSTR;
  float* st = states + r * NB;
  const int loff = (lane < 8) ? 8 * lane : 64;

  float4 qa[PF], qb[PF];
#pragma unroll
  for (int u = 0; u < PF; ++u) {
    qa[u] = *(const float4*)(base + u * CSTR + loff);
    qb[u] = *(const float4*)(base + u * CSTR + loff + 4);
  }

  float p = 0.f;
  for (int j = 0; j < 8; ++j) {       // 8 groups of 64 steps
    float sj = 0.f;                   // lane i holds state of block j*64+i
    for (int k = 0; k < 4; ++k) {     // 4 sub-groups of PF=16
#pragma unroll
      for (int u = 0; u < PF; ++u) {
        const int b = j * 64 + k * PF + u;
        const int i = k * PF + u;  // step within group (uniform)
        float f0 = fmaf(sl0, p, qa[u].x);
        float f1 = fmaf(sl1, p, qa[u].y);
        float f2 = fmaf(sl2, p, qa[u].z);
        float f3 = fmaf(sl3, p, qa[u].w);
        float f4 = fmaf(sl4, p, qb[u].x);
        float f5 = fmaf(sl5, p, qb[u].y);
        float f6 = fmaf(sl6, p, qb[u].z);
        float f7 = fmaf(sl7, p, qb[u].w);
        float m = fminf(fminf(fminf(f0, f1), f2),
                        fminf(fminf(fminf(f3, f4), f5), fminf(f6, f7)));
        m = fmin_dpp_step<0x111, 0xf>(m);  // row_shr:1
        m = fmin_dpp_step<0x112, 0xf>(m);  // row_shr:2
        m = fmin_dpp_step<0x114, 0xf>(m);  // row_shr:4 -> lane7 = min(0..7)
        m = fmin_dpp_step<0x111, 0xf>(m);  // fold lane7 agg into lane8
        sj = (lane == i) ? p : sj;  // state at START of block b (old p)
        p = __int_as_float(__builtin_amdgcn_readlane(__float_as_int(m), 8));
        // refill slot u for block b+PF (buffer padded; no tail branch)
        qa[u] = *(const float4*)(base + (b + PF) * CSTR + loff);
        qb[u] = *(const float4*)(base + (b + PF) * CSTR + loff + 4);
      }
    }
    st[j * 64 + lane] = sj;
  }
}

// K3: one wave per block; lane owns one frame (16 samples in regs); wave
// replays the 64-step recurrence from the block-start state; applies gain.
// OUT stores are NON-TEMPORAL (via native ext_vector_type -- HIP float4
// is a class and the builtin rejects it): keeps audio LLC-resident across
// replays so next replay's K1 reads warm (r12: warm 46.4us vs cold 74.5us).
__global__ __launch_bounds__(256) void k3_apply(
    const float* __restrict__ audio, const float* __restrict__ states,
    const float* __restrict__ p_thr, const float* __restrict__ p_ratio,
    const float* __restrict__ p_makeup, const float* __restrict__ p_att,
    const float* __restrict__ p_rel, float* __restrict__ out) {
  const int tid = threadIdx.x;
  const int lane = tid & 63;
  const int w = tid >> 6;
  const int gblk = blockIdx.x * 4 + w;  // 0..32767
  const int row = gblk >> 9;
  const int b = gblk & (NB - 1);
  const float thr = p_thr[0], ratio = p_ratio[0], mk = p_makeup[0];
  const float A = p_att[0], R = p_rel[0];
  const float oneA = 1.f - A, oneR = 1.f - R;
  const float gslope = (1.f / ratio) - 1.f;

  const size_t sbase = (size_t)row * T_DIM + (size_t)(b * LBLK + lane) * D_FAC;
  const float4* ap = (const float4*)(audio + sbase);
  float4 x0 = ap[0], x1 = ap[1], x2 = ap[2], x3 = ap[3];
  float s = sum_log2_4(x0) + sum_log2_4(x1) + sum_log2_4(x2) + sum_log2_4(x3);
  float xdb = s * (DB_PER_LOG2 / 16.f);
  float g = fminf(0.f, (xdb - thr) * gslope);

  float p = states[gblk];
  float m = 0.f;
  int gi = __float_as_int(g);
#pragma unroll
  for (int t = 0; t < LBLK; ++t) {
    float gt = __int_as_float(__builtin_amdgcn_readlane(gi, t));
    p = fminf(fmaf(A, p, oneA * gt), fmaf(R, p, oneR * gt));
    m = (lane == t) ? p : m;
  }
  float mult = exp2f((m + mk) * L2TEN_OVER20);
  vfloat4* op = (vfloat4*)(out + sbase);
  vfloat4 y0 = {x0.x * mult, x0.y * mult, x0.z * mult, x0.w * mult};
  vfloat4 y1 = {x1.x * mult, x1.y * mult, x1.z * mult, x1.w * mult};
  vfloat4 y2 = {x2.x * mult, x2.y * mult, x2.z * mult, x2.w * mult};
  vfloat4 y3 = {x3.x * mult, x3.y * mult, x3.z * mult, x3.w * mult};
  __builtin_nontemporal_store(y0, op + 0);
  __builtin_nontemporal_store(y1, op + 1);
  __builtin_nontemporal_store(y2, op + 2);
  __builtin_nontemporal_store(y3, op + 3);
}

extern "C" void kernel_launch(void* const* d_in, const int* in_sizes, int n_in,
                              void* d_out, int out_size, void* d_ws,
                              size_t ws_size, hipStream_t stream) {
  const float* audio = (const float*)d_in[0];
  const float* thr = (const float*)d_in[1];
  const float* ratio = (const float*)d_in[2];
  const float* makeup = (const float*)d_in[3];
  const float* att = (const float*)d_in[4];
  const float* rel = (const float*)d_in[5];
  float* out = (float*)d_out;

  const size_t CONSTS_BYTES = (size_t)NBLK_TOT * CSTR * sizeof(float);  // ~9.4 MB
  const size_t PAD_BYTES = (size_t)PF * CSTR * sizeof(float);           // tail prefetch pad
  const size_t STATES_BYTES = (size_t)NBLK_TOT * sizeof(float);         // 128 KB

  float* consts;
  float* states;
  if (ws_size >= CONSTS_BYTES + PAD_BYTES + STATES_BYTES) {
    consts = (float*)d_ws;
    states = (float*)((char*)d_ws + CONSTS_BYTES + PAD_BYTES);
  } else {
    consts = (float*)d_out;
    states = (float*)d_ws;
  }

  hipLaunchKernelGGL(k1_compose, dim3(8192), dim3(256), 0, stream, audio, thr,
                     ratio, att, rel, consts);
  hipLaunchKernelGGL(k2_scan, dim3(64), dim3(64), 0, stream, consts, states,
                     att, rel);
  hipLaunchKernelGGL(k3_apply, dim3(8192), dim3(256), 0, stream, audio, states,
                     thr, ratio, makeup, att, rel, out);
}

// Round 15
// 140.755 us; speedup vs baseline: 2.0001x; 1.2895x over previous
//
#include <hip/hip_runtime.h>

#define B_DIM 64
#define T_DIM 524288
#define D_FAC 16
#define LBLK 64          // frames per composed block
#define NB 512           // blocks per row
#define NBLK_TOT 32768   // total blocks (B*NB)
#define CSTR 72          // padded stride (floats) of one block map (16B-aligned)
#define PF 16            // K2 prefetch depth (blocks)
#define EPSV 1e-7f
#define BIGC 1e30f

// 20*log10(2)
#define DB_PER_LOG2 6.0205999132796239f
// log2(10)/20
#define L2TEN_OVER20 0.16609640474436813f

__device__ __forceinline__ float sum_log2_4(float4 x) {
  return __log2f(fabsf(x.x) + EPSV) + __log2f(fabsf(x.y) + EPSV) +
         __log2f(fabsf(x.z) + EPSV) + __log2f(fabsf(x.w) + EPSV);
}

template <int CTRL, int RM>
__device__ __forceinline__ float fmin_dpp_step(float v) {
  int vi = __float_as_int(v);
  int sh = __builtin_amdgcn_update_dpp(vi, vi, CTRL, RM, 0xf, false);
  return fminf(v, __int_as_float(sh));
}

// K1: one wave per 64-frame block; lane = class; class-parallel DP via DPP
// wave_shr:1. ca/cr broadcast from LDS via uniform-address float2 reads
// (r14: k1+k2 changes saved ~41us combined). Class 64 replicated into
// slots 64..71 so K2's lane 8 reads it as two float4.
__global__ __launch_bounds__(256) void k1_compose(
    const float* __restrict__ audio, const float* __restrict__ p_thr,
    const float* __restrict__ p_ratio, const float* __restrict__ p_att,
    const float* __restrict__ p_rel, float* __restrict__ consts) {
  __shared__ float cab[4][128];  // per wave: [2t]=ca_t, [2t+1]=cr_t
  const int tid = threadIdx.x;
  const int lane = tid & 63;
  const int w = tid >> 6;
  const int gblk = blockIdx.x * 4 + w;  // 0..32767
  const int row = gblk >> 9;
  const int b = gblk & (NB - 1);
  const float thr = p_thr[0];
  const float A = p_att[0], R = p_rel[0];
  const float oneA = 1.f - A, oneR = 1.f - R;
  const float gslope = (1.f / p_ratio[0]) - 1.f;

  const size_t sbase = (size_t)row * T_DIM + (size_t)(b * LBLK + lane) * D_FAC;
  const float4* ap = (const float4*)(audio + sbase);
  float s = sum_log2_4(ap[0]) + sum_log2_4(ap[1]) + sum_log2_4(ap[2]) +
            sum_log2_4(ap[3]);
  float xdb = s * (DB_PER_LOG2 / 16.f);
  float g = fminf(0.f, (xdb - thr) * gslope);

  // stage ca/cr for all t (same-wave ds_write -> ds_read, in-order)
  cab[w][2 * lane] = oneA * g;
  cab[w][2 * lane + 1] = oneR * g;

  const float2* cp = (const float2*)cab[w];
  float c = (lane == 0) ? 0.f : BIGC;
  float c64 = BIGC;
#pragma unroll
  for (int t = 0; t < LBLK; ++t) {
    float2 cc = cp[t];  // uniform address -> LDS broadcast
    float prev = __int_as_float(__builtin_amdgcn_update_dpp(
        __float_as_int(BIGC), __float_as_int(c), 0x138 /*wave_shr:1*/, 0xf,
        0xf, false));
    c64 = fminf(fmaf(A, c, cc.x), fmaf(R, c64, cc.y));  // c63_old on lane 63
    c = fminf(fmaf(A, prev, cc.x), fmaf(R, c, cc.y));
  }
  float* outp = consts + (size_t)gblk * CSTR;
  outp[lane] = c;
  if (lane == 63) {
#pragma unroll
    for (int j = 0; j < 8; ++j) outp[64 + j] = c64;
  }
}

// K2: serial scan, one wave per row. 8 classes per lane (lanes 0-7, two
// float4 each); lane 8 holds class 64 (replicated). Per step: 8 fma + min
// tree + 4 DPP stages + readlane(8). PF=16 register prefetch (~1300cyc
// latency cover for cross-XCD consts reads at 1 wave/CU). Lanes 9..63
// compute garbage never read by the reduce (row_shr pulls lower lanes).
__global__ __launch_bounds__(64) void k2_scan(const float* __restrict__ consts,
                                              float* __restrict__ states,
                                              const float* __restrict__ p_att,
                                              const float* __restrict__ p_rel) {
  const int r = blockIdx.x;
  const int lane = threadIdx.x;
  const float A = p_att[0], R = p_rel[0];
  const int cls0 = (lane < 8) ? 8 * lane : 64;
  float s0 = 1.f;
  for (int i = 0; i < 64; ++i) s0 *= (i < cls0) ? A : R;  // A^cls0 R^(64-cls0)
  const float rAR = A / R;
  const float sl0 = s0, sl1 = sl0 * rAR, sl2 = sl1 * rAR, sl3 = sl2 * rAR,
              sl4 = sl3 * rAR, sl5 = sl4 * rAR, sl6 = sl5 * rAR,
              sl7 = sl6 * rAR;

  const float* base = consts + (size_t)r * NB * CSTR;
  float* st = states + r * NB;
  const int loff = (lane < 8) ? 8 * lane : 64;

  float4 qa[PF], qb[PF];
#pragma unroll
  for (int u = 0; u < PF; ++u) {
    qa[u] = *(const float4*)(base + u * CSTR + loff);
    qb[u] = *(const float4*)(base + u * CSTR + loff + 4);
  }

  float p = 0.f;
  for (int j = 0; j < 8; ++j) {       // 8 groups of 64 steps
    float sj = 0.f;                   // lane i holds state of block j*64+i
    for (int k = 0; k < 4; ++k) {     // 4 sub-groups of PF=16
#pragma unroll
      for (int u = 0; u < PF; ++u) {
        const int b = j * 64 + k * PF + u;
        const int i = k * PF + u;  // step within group (uniform)
        float f0 = fmaf(sl0, p, qa[u].x);
        float f1 = fmaf(sl1, p, qa[u].y);
        float f2 = fmaf(sl2, p, qa[u].z);
        float f3 = fmaf(sl3, p, qa[u].w);
        float f4 = fmaf(sl4, p, qb[u].x);
        float f5 = fmaf(sl5, p, qb[u].y);
        float f6 = fmaf(sl6, p, qb[u].z);
        float f7 = fmaf(sl7, p, qb[u].w);
        float m = fminf(fminf(fminf(f0, f1), f2),
                        fminf(fminf(fminf(f3, f4), f5), fminf(f6, f7)));
        m = fmin_dpp_step<0x111, 0xf>(m);  // row_shr:1
        m = fmin_dpp_step<0x112, 0xf>(m);  // row_shr:2
        m = fmin_dpp_step<0x114, 0xf>(m);  // row_shr:4 -> lane7 = min(0..7)
        m = fmin_dpp_step<0x111, 0xf>(m);  // fold lane7 agg into lane8
        sj = (lane == i) ? p : sj;  // state at START of block b (old p)
        p = __int_as_float(__builtin_amdgcn_readlane(__float_as_int(m), 8));
        // refill slot u for block b+PF (buffer padded; no tail branch)
        qa[u] = *(const float4*)(base + (b + PF) * CSTR + loff);
        qb[u] = *(const float4*)(base + (b + PF) * CSTR + loff + 4);
      }
    }
    st[j * 64 + lane] = sj;
  }
}

// K3: one wave per block; lane owns one frame (16 samples in regs); wave
// replays the 64-step recurrence from the block-start state; applies gain.
// Plain float4 stores (L2-coalesced). r14 ERRATA: non-temporal stores
// bypass L2 write-coalescing -> partial-line RMW at HBM (WRITE_SIZE 2x,
// k3 20 -> 99us). Do NOT use NT stores for dense sequential output.
__global__ __launch_bounds__(256) void k3_apply(
    const float* __restrict__ audio, const float* __restrict__ states,
    const float* __restrict__ p_thr, const float* __restrict__ p_ratio,
    const float* __restrict__ p_makeup, const float* __restrict__ p_att,
    const float* __restrict__ p_rel, float* __restrict__ out) {
  const int tid = threadIdx.x;
  const int lane = tid & 63;
  const int w = tid >> 6;
  const int gblk = blockIdx.x * 4 + w;  // 0..32767
  const int row = gblk >> 9;
  const int b = gblk & (NB - 1);
  const float thr = p_thr[0], ratio = p_ratio[0], mk = p_makeup[0];
  const float A = p_att[0], R = p_rel[0];
  const float oneA = 1.f - A, oneR = 1.f - R;
  const float gslope = (1.f / ratio) - 1.f;

  const size_t sbase = (size_t)row * T_DIM + (size_t)(b * LBLK + lane) * D_FAC;
  const float4* ap = (const float4*)(audio + sbase);
  float4 x0 = ap[0], x1 = ap[1], x2 = ap[2], x3 = ap[3];
  float s = sum_log2_4(x0) + sum_log2_4(x1) + sum_log2_4(x2) + sum_log2_4(x3);
  float xdb = s * (DB_PER_LOG2 / 16.f);
  float g = fminf(0.f, (xdb - thr) * gslope);

  float p = states[gblk];
  float m = 0.f;
  int gi = __float_as_int(g);
#pragma unroll
  for (int t = 0; t < LBLK; ++t) {
    float gt = __int_as_float(__builtin_amdgcn_readlane(gi, t));
    p = fminf(fmaf(A, p, oneA * gt), fmaf(R, p, oneR * gt));
    m = (lane == t) ? p : m;
  }
  float mult = exp2f((m + mk) * L2TEN_OVER20);
  float4* op = (float4*)(out + sbase);
  float4 y0, y1, y2, y3;
  y0.x = x0.x * mult; y0.y = x0.y * mult; y0.z = x0.z * mult; y0.w = x0.w * mult;
  y1.x = x1.x * mult; y1.y = x1.y * mult; y1.z = x1.z * mult; y1.w = x1.w * mult;
  y2.x = x2.x * mult; y2.y = x2.y * mult; y2.z = x2.z * mult; y2.w = x2.w * mult;
  y3.x = x3.x * mult; y3.y = x3.y * mult; y3.z = x3.z * mult; y3.w = x3.w * mult;
  op[0] = y0; op[1] = y1; op[2] = y2; op[3] = y3;
}

extern "C" void kernel_launch(void* const* d_in, const int* in_sizes, int n_in,
                              void* d_out, int out_size, void* d_ws,
                              size_t ws_size, hipStream_t stream) {
  const float* audio = (const float*)d_in[0];
  const float* thr = (const float*)d_in[1];
  const float* ratio = (const float*)d_in[2];
  const float* makeup = (const float*)d_in[3];
  const float* att = (const float*)d_in[4];
  const float* rel = (const float*)d_in[5];
  float* out = (float*)d_out;

  const size_t CONSTS_BYTES = (size_t)NBLK_TOT * CSTR * sizeof(float);  // ~9.4 MB
  const size_t PAD_BYTES = (size_t)PF * CSTR * sizeof(float);           // tail prefetch pad
  const size_t STATES_BYTES = (size_t)NBLK_TOT * sizeof(float);         // 128 KB

  float* consts;
  float* states;
  if (ws_size >= CONSTS_BYTES + PAD_BYTES + STATES_BYTES) {
    consts = (float*)d_ws;
    states = (float*)((char*)d_ws + CONSTS_BYTES + PAD_BYTES);
  } else {
    consts = (float*)d_out;
    states = (float*)d_ws;
  }

  hipLaunchKernelGGL(k1_compose, dim3(8192), dim3(256), 0, stream, audio, thr,
                     ratio, att, rel, consts);
  hipLaunchKernelGGL(k2_scan, dim3(64), dim3(64), 0, stream, consts, states,
                     att, rel);
  hipLaunchKernelGGL(k3_apply, dim3(8192), dim3(256), 0, stream, audio, states,
                     thr, ratio, makeup, att, rel, out);
}